// Round 1
// baseline (162.351 us; speedup 1.0000x reference)
//
#include <hip/hip_runtime.h>

#define T_LEN  16384
#define B_N    1024
#define CHUNKS 64
#define CL     (T_LEN / CHUNKS)   // 256 steps per chunk
#define WARM   128                // warmup steps for chunks j>0

__device__ __forceinline__ float fast_sigmoid(float x) {
    // 1 / (1 + exp(-x)) via v_exp_f32 (2^x) + v_rcp_f32
    float t = __builtin_amdgcn_exp2f(-1.4426950408889634f * x);
    return __builtin_amdgcn_rcpf(1.0f + t);
}

__device__ __forceinline__ float fast_tanh(float x) {
    // 1 - 2/(1 + exp(2x)); saturates correctly at +/-inf (exp2 overflow -> inf -> rcp -> 0)
    float t = __builtin_amdgcn_exp2f(2.8853900817779268f * x);
    return fmaf(-2.0f, __builtin_amdgcn_rcpf(1.0f + t), 1.0f);
}

__global__ __launch_bounds__(256) void lstm_chunk_kernel(
    const float* __restrict__ x,
    const float* __restrict__ w_ih,
    const float* __restrict__ w_hh,
    const float* __restrict__ b_ih,
    const float* __restrict__ b_hh,
    const float* __restrict__ Wlin,
    const float* __restrict__ blin,
    float* __restrict__ y)
{
    const int gid = blockIdx.x * 256 + threadIdx.x;
    const int j = gid >> 10;        // chunk index   (uniform per block: B_N=1024 >= block)
    const int b = gid & (B_N - 1);  // sequence index (lane-consecutive -> per-lane row streaming)

    // Scalar parameters (wave-uniform -> scalar loads)
    const float wi = w_ih[0], wf = w_ih[1], wg = w_ih[2], wo = w_ih[3];
    const float ui = w_hh[0], uf = w_hh[1], ug = w_hh[2], uo = w_hh[3];
    const float bi = b_ih[0] + b_hh[0];
    const float bf = b_ih[1] + b_hh[1];
    const float bg = b_ih[2] + b_hh[2];
    const float bo = b_ih[3] + b_hh[3];
    const float Wy = Wlin[0], by = blin[0];

    const int start  = j * CL;
    const int warm   = j ? WARM : 0;          // chunk 0 starts from the true zero state
    const int wstart = start - warm;
    const int nblk   = (CL + warm) >> 4;      // 16 or 24 blocks of 16 steps
    const int nwarm  = warm >> 4;             // 0 or 8 warmup blocks (no writes)

    const float* xp = x + (size_t)b * T_LEN + wstart;  // 64B-aligned (wstart % 16 == 0)
    float*       yp = y + (size_t)b * T_LEN + start;

    float cur[16], nxt[16] = {};
    {
        const float4* c0 = (const float4*)xp;
        *(float4*)(cur + 0)  = c0[0];
        *(float4*)(cur + 4)  = c0[1];
        *(float4*)(cur + 8)  = c0[2];
        *(float4*)(cur + 12) = c0[3];
    }

    float h = 0.0f, c = 0.0f;

    for (int blk = 0; blk < nblk; ++blk) {
        // Prefetch the next 16 x-values; consumed ~16 dependent LSTM steps later,
        // which hides the ~900-cycle HBM miss latency.
        if (blk + 1 < nblk) {
            const float4* nx = (const float4*)(xp + ((blk + 1) << 4));
            *(float4*)(nxt + 0)  = nx[0];
            *(float4*)(nxt + 4)  = nx[1];
            *(float4*)(nxt + 8)  = nx[2];
            *(float4*)(nxt + 12) = nx[3];
        }

        float yv[16];
        #pragma unroll
        for (int k = 0; k < 16; ++k) {
            const float xv = cur[k];
            const float pi = fmaf(h, ui, fmaf(xv, wi, bi));
            const float pf = fmaf(h, uf, fmaf(xv, wf, bf));
            const float pg = fmaf(h, ug, fmaf(xv, wg, bg));
            const float po = fmaf(h, uo, fmaf(xv, wo, bo));
            const float gi = fast_sigmoid(pi);
            const float gf = fast_sigmoid(pf);
            const float gg = fast_tanh(pg);
            const float go = fast_sigmoid(po);
            c = fmaf(gf, c, gi * gg);
            h = go * fast_tanh(c);
            yv[k] = fmaf(h, Wy, by);
        }

        if (blk >= nwarm) {   // uniform branch (j uniform per block)
            float4* yo = (float4*)(yp + ((blk - nwarm) << 4));
            yo[0] = *(float4*)(yv + 0);
            yo[1] = *(float4*)(yv + 4);
            yo[2] = *(float4*)(yv + 8);
            yo[3] = *(float4*)(yv + 12);
        }

        #pragma unroll
        for (int k = 0; k < 16; ++k) cur[k] = nxt[k];
    }
}

extern "C" void kernel_launch(void* const* d_in, const int* in_sizes, int n_in,
                              void* d_out, int out_size, void* d_ws, size_t ws_size,
                              hipStream_t stream) {
    const float* x    = (const float*)d_in[0];
    const float* w_ih = (const float*)d_in[1];
    const float* w_hh = (const float*)d_in[2];
    const float* b_ih = (const float*)d_in[3];
    const float* b_hh = (const float*)d_in[4];
    const float* Wlin = (const float*)d_in[5];
    const float* blin = (const float*)d_in[6];
    float* y = (float*)d_out;

    const int total_threads = B_N * CHUNKS;          // 65536
    lstm_chunk_kernel<<<dim3(total_threads / 256), dim3(256), 0, stream>>>(
        x, w_ih, w_hh, b_ih, b_hh, Wlin, blin, y);
}

// Round 2
// 147.107 us; speedup vs baseline: 1.1036x; 1.1036x over previous
//
#include <hip/hip_runtime.h>

#define T_LEN  16384
#define B_N    1024
#define CHUNKS 256
#define CL     (T_LEN / CHUNKS)   // 64 steps per chunk
#define WARM   48                 // warmup steps for chunks j>0 (contraction ~0.7^48 ~ 4e-8)

__device__ __forceinline__ float fast_sigmoid(float x) {
    // 1 / (1 + exp(-x)) via v_exp_f32 (2^x) + v_rcp_f32
    float t = __builtin_amdgcn_exp2f(-1.4426950408889634f * x);
    return __builtin_amdgcn_rcpf(1.0f + t);
}

__device__ __forceinline__ float fast_tanh(float x) {
    // 1 - 2/(1 + exp(2x)); saturates correctly at +/-inf (exp2 overflow -> inf -> rcp -> 0)
    float t = __builtin_amdgcn_exp2f(2.8853900817779268f * x);
    return fmaf(-2.0f, __builtin_amdgcn_rcpf(1.0f + t), 1.0f);
}

__global__ __launch_bounds__(256) void lstm_chunk_kernel(
    const float* __restrict__ x,
    const float* __restrict__ w_ih,
    const float* __restrict__ w_hh,
    const float* __restrict__ b_ih,
    const float* __restrict__ b_hh,
    const float* __restrict__ Wlin,
    const float* __restrict__ blin,
    float* __restrict__ y)
{
    const int gid = blockIdx.x * 256 + threadIdx.x;
    const int j = gid >> 10;        // chunk index   (uniform per 256-block: 256 | 1024)
    const int b = gid & (B_N - 1);  // sequence index (lane-consecutive -> coalesced-ish row streaming)

    // Scalar parameters (wave-uniform -> scalar loads)
    const float wi = w_ih[0], wf = w_ih[1], wg = w_ih[2], wo = w_ih[3];
    const float ui = w_hh[0], uf = w_hh[1], ug = w_hh[2], uo = w_hh[3];
    const float bi = b_ih[0] + b_hh[0];
    const float bf = b_ih[1] + b_hh[1];
    const float bg = b_ih[2] + b_hh[2];
    const float bo = b_ih[3] + b_hh[3];
    const float Wy = Wlin[0], by = blin[0];

    const int start  = j * CL;
    const int warm   = j ? WARM : 0;          // chunk 0 starts from the true zero state
    const int wstart = start - warm;
    const int nblk   = (CL + warm) >> 4;      // 4 or 7 blocks of 16 steps
    const int nwarm  = warm >> 4;             // 0 or 3 warmup blocks (no writes)

    const float* xp = x + (size_t)b * T_LEN + wstart;  // 64B-aligned (wstart % 16 == 0)
    float*       yp = y + (size_t)b * T_LEN + start;

    float cur[16], nxt[16] = {};
    {
        const float4* c0 = (const float4*)xp;
        *(float4*)(cur + 0)  = c0[0];
        *(float4*)(cur + 4)  = c0[1];
        *(float4*)(cur + 8)  = c0[2];
        *(float4*)(cur + 12) = c0[3];
    }

    float h = 0.0f, c = 0.0f;

    for (int blk = 0; blk < nblk; ++blk) {
        // Prefetch the next 16 x-values; consumed ~16 dependent LSTM steps (x4 waves
        // of wall time at 4 waves/SIMD) later -> hides the ~900-cycle HBM miss.
        if (blk + 1 < nblk) {
            const float4* nx = (const float4*)(xp + ((blk + 1) << 4));
            *(float4*)(nxt + 0)  = nx[0];
            *(float4*)(nxt + 4)  = nx[1];
            *(float4*)(nxt + 8)  = nx[2];
            *(float4*)(nxt + 12) = nx[3];
        }

        float yv[16];
        #pragma unroll
        for (int k = 0; k < 16; ++k) {
            const float xv = cur[k];
            const float pi = fmaf(h, ui, fmaf(xv, wi, bi));
            const float pf = fmaf(h, uf, fmaf(xv, wf, bf));
            const float pg = fmaf(h, ug, fmaf(xv, wg, bg));
            const float po = fmaf(h, uo, fmaf(xv, wo, bo));
            const float gi = fast_sigmoid(pi);
            const float gf = fast_sigmoid(pf);
            const float gg = fast_tanh(pg);
            const float go = fast_sigmoid(po);
            c = fmaf(gf, c, gi * gg);
            h = go * fast_tanh(c);
            yv[k] = fmaf(h, Wy, by);
        }

        if (blk >= nwarm) {   // uniform branch (j uniform per block)
            float4* yo = (float4*)(yp + ((blk - nwarm) << 4));
            yo[0] = *(float4*)(yv + 0);
            yo[1] = *(float4*)(yv + 4);
            yo[2] = *(float4*)(yv + 8);
            yo[3] = *(float4*)(yv + 12);
        }

        #pragma unroll
        for (int k = 0; k < 16; ++k) cur[k] = nxt[k];
    }
}

extern "C" void kernel_launch(void* const* d_in, const int* in_sizes, int n_in,
                              void* d_out, int out_size, void* d_ws, size_t ws_size,
                              hipStream_t stream) {
    const float* x    = (const float*)d_in[0];
    const float* w_ih = (const float*)d_in[1];
    const float* w_hh = (const float*)d_in[2];
    const float* b_ih = (const float*)d_in[3];
    const float* b_hh = (const float*)d_in[4];
    const float* Wlin = (const float*)d_in[5];
    const float* blin = (const float*)d_in[6];
    float* y = (float*)d_out;

    const int total_threads = B_N * CHUNKS;          // 262144 -> 4096 waves -> 4/SIMD
    lstm_chunk_kernel<<<dim3(total_threads / 256), dim3(256), 0, stream>>>(
        x, w_ih, w_hh, b_ih, b_hh, Wlin, blin, y);
}